// Round 5
// baseline (125.874 us; speedup 1.0000x reference)
//
#include <hip/hip_runtime.h>

// DatasetProjector: per-example Conv1d(200ch->512-of-4096, k=3, pad=1) + bias + GELU,
// computing only dataset_id[b]'s 512-channel slice (8x algebraic cut).
//
// R10: hide the terminal store burst. R6-R9 post-mortem: four schedule/locality
// attacks null -> conv's unattacked cost is the phase-locked terminal epilogue:
// 64MB of output written AFTER all compute, all 512 blocks simultaneously ->
// ~10.2us serial HBM burst with zero overlap. Fix: each block processes its
// 256-t tile as TWO 128-t halves run to completion (chunks 0-6 + epilogue each);
// epilogue(0)'s 32MB drains during half-1's ~11us of compute (44MB/11us = 4TB/s
// < 6.3 headroom). Per-output FP accumulation order unchanged -> bit-identical.
// W now staged per-chunk into LDS (24KB dbuf, wave-level global_load_lds per
// 1KB frag-row): W-frag reads are ~100cy ds_reads prefetched at chunk top, so
// the halved per-(c,tap) MFMA count (16) does not re-expose R7's W L2 latency.
// Total W traffic unchanged (24KB x 14 = 336KB/block, L2-hot via R9's XCD map).
// X granule swizzle s = p ^ ((row>>1)&3) kept verbatim (R4 measured 0 conflicts).
// LDS 16.6K (X dbuf) + 49.2K (W dbuf) = 65.8KB -> still 2 blocks/CU; acc halves
// to 64 VGPR.
// Note: ~78us/iter of total dur is harness d_ws/d_out re-poison fills (uncontrollable).

typedef unsigned short u16;
typedef __attribute__((ext_vector_type(8))) short bf16x8;
typedef __attribute__((ext_vector_type(4))) float f32x4;

#define CIN 200
#define CINP 224        // padded channels = 7 chunks of 32
#define T 1024
#define BATCH 32
#define MD 512
#define XT_ROWS 1026    // row t1 = t+1; rows 0 and 1025 are zeros
#define NCHUNK 7
#define XP_PITCH 202    // prep LDS pitch in u16 -> 101 dwords (odd => conflict-free)
#define TT 256          // t-tile per block (two 128-t halves)
#define HROWS 130       // staged x rows per half (t0h-1 .. t0h+128)
#define XG_H (HROWS * 4)      // 520 16B granules = 8.3 KB per buffer
#define WFRAGS 24             // 2 wm-halves x 4 mi x 3 taps, 1KB frag-rows
#define WOB 256               // 4096/16 o-blocks
#define WF_PER_OB (21 * 512)  // 3 taps x 7 chunks x 64 lanes x 8 u16 = 10752 u16/oblk

__device__ __forceinline__ u16 f2bf(float f) {
    unsigned u = __float_as_uint(f);
    u += 0x7FFFu + ((u >> 16) & 1u);   // RNE
    return (u16)(u >> 16);
}

// async global(16B) -> LDS, dest = wave-uniform base + lane*16
__device__ __forceinline__ void g2l16(void* lds, const void* g) {
    __builtin_amdgcn_global_load_lds(
        (const __attribute__((address_space(1))) unsigned int*)(uintptr_t)g,
        (__attribute__((address_space(3))) unsigned int*)(unsigned)(uintptr_t)lds,
        16, 0, 0);
}

// ---- fused prep: blocks [0,512) transpose x -> xt[b][t+1][224] bf16;
//      blocks [512, 512+256) transform W[o][i][k] -> wf fragment-ordered bf16 ----
__global__ __launch_bounds__(256) void prep(const float* __restrict__ x,
                                            const float* __restrict__ W,
                                            u16* __restrict__ xt,
                                            u16* __restrict__ wf) {
    __shared__ __align__(16) unsigned char smem[16 * 673 * 4];  // 43 KB, unioned
    const int tid = threadIdx.x;
    if (blockIdx.x < 512) {
        u16* tile = (u16*)smem;   // uses 64*202*2 = 25.9 KB of smem
        const int b  = blockIdx.x >> 4;
        const int bx = blockIdx.x & 15;
        const int t0 = bx * 64;
        const int tl = tid & 63;       // t within tile (lane -> coalesced x reads)
        const int w  = tid >> 6;
        const float* xb = x + (size_t)b * CIN * T + t0 + tl;
        for (int i = w; i < CIN; i += 4)                 // LDS row pitch 101 dwords (odd) -> conflict-free
            tile[tl * XP_PITCH + i] = f2bf(xb[(size_t)i * T]);
        __syncthreads();
        u16* xrow = xt + ((size_t)b * XT_ROWS + 1 + t0) * CINP;
        for (int it = 0; it < 16; ++it) {
            int r = it * 4 + w;
            if (tl < 56) {                               // 56 lanes x ushort4 = 224 ch
                ushort4 v = {0, 0, 0, 0};
                if (tl < 50) {                           // 50*4 = 200 valid channels
                    const u16* p = tile + r * XP_PITCH + tl * 4;
                    v.x = p[0]; v.y = p[1]; v.z = p[2]; v.w = p[3];
                }
                *(ushort4*)(xrow + (size_t)r * CINP + tl * 4) = v;
            }
        }
        if (bx == 0 && tid < 112)
            ((unsigned*)(xt + (size_t)b * XT_ROWS * CINP))[tid] = 0;          // t = -1 row
        if (bx == 15 && tid < 112)
            ((unsigned*)(xt + ((size_t)b * XT_ROWS + 1025) * CINP))[tid] = 0; // t = 1024 row
    } else {
        // W -> wf: one block per oblk (16 o-rows). Coalesced f32 load -> LDS ->
        // fully-coalesced u16 store in fragment order.
        float* wtile = (float*)smem;                     // [16][673] padded (673%32==1)
        const int ob = blockIdx.x - 512;
        const float* wp = W + (size_t)ob * 16 * 768;     // W rows o in [ob*16, ob*16+16)
        for (int j = tid; j < 16 * 672; j += 256) {      // only i<224 (first 672 f32/row) used
            int o = j / 672, r = j - o * 672;
            wtile[o * 673 + r] = wp[(size_t)o * 768 + r];
        }
        __syncthreads();
        u16* wo = wf + (size_t)ob * WF_PER_OB;
        for (int j = tid; j < WF_PER_OB; j += 256) {     // j = ((k*7+c)*64+lane)*8+e
            int e    = j & 7;
            int lane = (j >> 3) & 63;
            int kc   = j >> 9;                           // k*7 + c  (< 21)
            int cc   = kc % 7, k = kc / 7;
            int l = lane & 15, q = lane >> 4;
            int i = cc * 32 + q * 8 + e;                 // channel index
            // A-fragment semantics: lane (l,q) holds A[row=l][K=q*8+e] of o-row ob*16+l
            wo[j] = f2bf(wtile[l * 673 + i * 3 + k]);
        }
    }
}

// ---- main: per-example MFMA conv-GEMM, 128m x (2 x 128t) per block, 512 blocks ----
__global__ __launch_bounds__(256, 2) void conv_mfma(const u16* __restrict__ xt,
                                                    const u16* __restrict__ wf,
                                                    const int* __restrict__ dsid,
                                                    const float* __restrict__ bias,
                                                    float* __restrict__ out) {
    __shared__ __align__(16) u16 xs[2 * XG_H * 8];       // 16.6 KB: X dbuf
    __shared__ __align__(16) u16 wsm[2 * WFRAGS * 512];  // 49.2 KB: W dbuf

    const int tid = threadIdx.x;
    const int wave = tid >> 6, lane = tid & 63;
    const int l = lane & 15, quad = lane >> 4;
    const int wm  = (wave & 1) * 64;       // wave m offset (2 m-waves)
    const int wti = (wave >> 1) * 64;      // wave t offset within 128-t half

    // XCD regroup (R9): XCD k owns 4 complete b's; same-(b,t) m-quads same-XCD.
    const int id  = blockIdx.x;          // 512 = 8 xcd x 4 b x 4 m x 4 t
    const int xcd = id & 7;
    const int j   = id >> 3;             // 0..63 within XCD
    const int b   = xcd * 4 + (j >> 4);
    const int m0  = ((j >> 2) & 3) * 128;
    const int t0  = (j & 3) * TT;
    const int d  = dsid[b];
    const int obase = d * MD + m0;

    f32x4 acc[4][4];
#pragma unroll
    for (int mi = 0; mi < 4; ++mi)
#pragma unroll
        for (int ti = 0; ti < 4; ++ti) acc[mi][ti] = (f32x4){0.f, 0.f, 0.f, 0.f};

    const u16* xbase = xt + ((size_t)b * XT_ROWS + t0) * CINP;  // half h adds 128*CINP
    const u16* wfb0  = wf + (size_t)((obase) >> 4) * WF_PER_OB + lane * 8;
    const u16* wfb64 = wf + (size_t)((obase + 64) >> 4) * WF_PER_OB + lane * 8;

    // hoisted X staging addresses (h=0,c=0); advance = h*128*CINP + c*32 u16
    const u16* xsrc[3]; unsigned xdof[3];
#pragma unroll
    for (int k = 0; k < 3; ++k) {
        int g = tid + k * 256;
        int r = g >> 2, p = g & 3, s = p ^ ((r >> 1) & 3);
        if (g < XG_H) { xsrc[k] = xbase + (size_t)r * CINP + s * 8; xdof[k] = (g & ~63) * 8; }
        else          { xsrc[k] = xbase;                            xdof[k] = 0; }
    }

    auto stageX = [&](int bsel, int h, int c) {
        const int adv = h * 128 * CINP + c * 32;
        u16* base = xs + bsel * (XG_H * 8);
        g2l16(base + xdof[0], xsrc[0] + adv);
        g2l16(base + xdof[1], xsrc[1] + adv);
        if (tid + 512 < XG_H) g2l16(base + xdof[2], xsrc[2] + adv);
    };
    auto stageW = [&](int bsel, int c) {
        // 24 x 1KB frag-rows; wave w stages f = 6w .. 6w+5 (wave-uniform dests)
#pragma unroll
        for (int j2 = 0; j2 < 6; ++j2) {
            int f   = wave * 6 + j2;
            int rr  = (f >= 12) ? f - 12 : f;
            int mi  = rr >> 2 ? (rr / 3) : (rr / 3);   // rr/3
            int tap = rr - mi * 3;
            const u16* src = ((f >= 12) ? wfb64 : wfb0) + ((mi * 21 + tap * 7 + c) << 9);
            g2l16(wsm + bsel * (WFRAGS * 512) + f * 512, src);
        }
    };

    // epilogue: +bias, sigmoid-form tanh-GELU (exp2-folded, branchless), f32 store
    float bvv[4][4];
#pragma unroll
    for (int mi = 0; mi < 4; ++mi)
#pragma unroll
        for (int r = 0; r < 4; ++r)
            bvv[mi][r] = bias[obase + wm + mi * 16 + quad * 4 + r];

    auto epi = [&](int h) {
#pragma unroll
        for (int mi = 0; mi < 4; ++mi)
#pragma unroll
            for (int ti = 0; ti < 4; ++ti) {
                int t = t0 + h * 128 + wti + ti * 16 + l;
#pragma unroll
                for (int r = 0; r < 4; ++r) {
                    int m = wm + mi * 16 + quad * 4 + r;
                    float v = acc[mi][ti][r] + bvv[mi][r];
                    float p2 = v * v;
                    // exp(-z), z = v*(1.59577 + 0.0713548 v^2), folded to exp2
                    float z2 = v * fmaf(p2, -0.10295089f, -2.30243665f);
                    float e = __builtin_amdgcn_exp2f(z2);
                    float g = v * __builtin_amdgcn_rcpf(1.0f + e);   // v * sigmoid(z)
                    out[((size_t)(b * MD + m0 + m)) * T + t] = g;
                }
            }
    };

    stageX(0, 0, 0); stageW(0, 0);
    __syncthreads();

#pragma unroll
    for (int h = 0; h < 2; ++h) {
#pragma unroll
        for (int c = 0; c < NCHUNK; ++c) {
            const int cc   = h * NCHUNK + c;
            const int bsel = cc & 1;
            if (cc == NCHUNK) {
                epi(0);                              // stores drain under half-1 compute
#pragma unroll
                for (int mi = 0; mi < 4; ++mi)
#pragma unroll
                    for (int ti = 0; ti < 4; ++ti) acc[mi][ti] = (f32x4){0.f, 0.f, 0.f, 0.f};
            }
            if (cc + 1 < 2 * NCHUNK) {               // prefetch next chunk (possibly next half)
                const int h2 = (c == NCHUNK - 1) ? h + 1 : h;
                const int c2 = (c == NCHUNK - 1) ? 0 : c + 1;
                stageX(bsel ^ 1, h2, c2);
                stageW(bsel ^ 1, c2);
            }
            // W frags for this chunk from LDS (contiguous 1KB/wave reads, 2-way free)
            bf16x8 wfr[4][3];
            const u16* wb = wsm + bsel * (WFRAGS * 512) + (wm ? 12 * 512 : 0) + lane * 8;
#pragma unroll
            for (int mi = 0; mi < 4; ++mi)
#pragma unroll
                for (int tap = 0; tap < 3; ++tap)
                    wfr[mi][tap] = *(const bf16x8*)(wb + (mi * 3 + tap) * 512);

            const u16* xb = xs + bsel * (XG_H * 8);
#pragma unroll
            for (int tap = 0; tap < 3; ++tap) {
#pragma unroll
                for (int ti = 0; ti < 4; ++ti) {
                    int row = wti + tap + ti * 16 + l;
                    bf16x8 bv = *(const bf16x8*)(xb + ((size_t)row * 4 + (quad ^ ((row >> 1) & 3))) * 8);
                    __builtin_amdgcn_s_setprio(1);
#pragma unroll
                    for (int mi = 0; mi < 4; ++mi)
                        acc[mi][ti] = __builtin_amdgcn_mfma_f32_16x16x32_bf16(wfr[mi][tap], bv, acc[mi][ti], 0, 0, 0);
                    __builtin_amdgcn_s_setprio(0);
                }
            }
            if (cc + 1 < 2 * NCHUNK) __syncthreads();
        }
    }
    epi(1);
}

extern "C" void kernel_launch(void* const* d_in, const int* in_sizes, int n_in,
                              void* d_out, int out_size, void* d_ws, size_t ws_size,
                              hipStream_t stream) {
    const float* x    = (const float*)d_in[0];
    const int*   dsid = (const int*)d_in[1];
    const float* W    = (const float*)d_in[2];
    const float* bias = (const float*)d_in[3];
    float* out = (float*)d_out;

    u16* xt = (u16*)d_ws;                                // 32*1026*224*2 = 14.7 MB
    u16* wf = xt + (size_t)BATCH * XT_ROWS * CINP;       // 256*21*512*2  =  5.5 MB

    prep<<<512 + WOB, 256, 0, stream>>>(x, W, xt, wf);
    conv_mfma<<<512, 256, 0, stream>>>(xt, wf, dsid, bias, out);
}